// Round 4
// baseline (400.780 us; speedup 1.0000x reference)
//
#include <hip/hip_runtime.h>
#include <hip/hip_bf16.h>

// Problem constants: B=16, C=256, H=W=64, LOC=4096, DOWN=1024, C8=32, C2=128.

typedef short s8v __attribute__((ext_vector_type(8)));   // 8 x bf16 bits (4 VGPRs)
typedef float f4v __attribute__((ext_vector_type(4)));   // 4 x fp32 acc

#define MFMA16(a, b, c) __builtin_amdgcn_mfma_f32_16x16x32_bf16((a), (b), (c), 0, 0, 0)
#define LOG2E 1.4426950408889634f

__device__ __forceinline__ unsigned short f2b(float f) {
    __hip_bfloat16 h = __float2bfloat16(f);
    return *reinterpret_cast<unsigned short*>(&h);
}
__device__ __forceinline__ float b2f(unsigned short u) {
    union { unsigned int i; float f; } v; v.i = ((unsigned int)u) << 16; return v.f;
}

// ---------------------------------------------------------------------------
// Weight prep: concat q/k/v weights -> bf16 [192][256], bias fp32 [192],
// val2_w -> bf16 [256][128]. K rows (32..63) and K bias pre-scaled by log2(e)
// so downstream softmax uses exp2 directly.
// ---------------------------------------------------------------------------
__global__ void prep_weights(const float* __restrict__ qw, const float* __restrict__ qb,
                             const float* __restrict__ kw, const float* __restrict__ kb,
                             const float* __restrict__ vw, const float* __restrict__ vb,
                             const float* __restrict__ v2w,
                             unsigned short* __restrict__ wqkv, float* __restrict__ bias,
                             unsigned short* __restrict__ w2b) {
    int i = blockIdx.x * 256 + threadIdx.x;
    if (i < 49152) {                       // 192*256
        int r = i >> 8, c = i & 255; float v;
        if (r < 32)       v = qw[r * 256 + c];
        else if (r < 64)  v = kw[(r - 32) * 256 + c] * LOG2E;
        else              v = vw[(r - 64) * 256 + c];
        wqkv[i] = f2b(v);
    } else if (i < 49152 + 32768) {        // 256*128
        int k = i - 49152; w2b[k] = f2b(v2w[k]);
    } else if (i < 49152 + 32768 + 192) {
        int r = i - 49152 - 32768;
        bias[r] = (r < 32) ? qb[r] : (r < 64 ? kb[r - 32] * LOG2E : vb[r - 64]);
    }
}

// ---------------------------------------------------------------------------
// Generic batched transpose: src [R][C] (row-major, per batch) -> dst [C][R] bf16.
// ---------------------------------------------------------------------------
template <typename T>
__global__ __launch_bounds__(256) void transpose_to_bf16(const T* __restrict__ src,
                                                         unsigned short* __restrict__ dst,
                                                         int R, int C) {
    __shared__ float tile[64][65];
    int b = blockIdx.z;
    size_t base = (size_t)b * R * C;
    int r0 = blockIdx.x * 64, c0 = blockIdx.y * 64;
    int tr = threadIdx.x >> 6, tc = threadIdx.x & 63;
    for (int i = 0; i < 16; ++i) {
        int rl = i * 4 + tr;
        T v = src[base + (size_t)(r0 + rl) * C + c0 + tc];
        float f;
        if constexpr (sizeof(T) == 2) f = b2f((unsigned short)v); else f = (float)v;
        tile[rl][tc] = f;
    }
    __syncthreads();
    for (int i = 0; i < 16; ++i) {
        int cl = i * 4 + tr;
        dst[base + (size_t)(c0 + cl) * R + r0 + tc] = f2b(tile[tc][cl]);
    }
}

// ---------------------------------------------------------------------------
// V transpose with fused column scale: vf raw-view [1024 j][128 c] ->
// vt[c][j] = vf_flat[j*128+c] * rs[j].
// ---------------------------------------------------------------------------
__global__ __launch_bounds__(256) void transpose_scale_v(const unsigned short* __restrict__ src,
                                                         const float* __restrict__ rs,
                                                         unsigned short* __restrict__ dst) {
    __shared__ float tile[64][65];
    int b = blockIdx.z;
    size_t base = (size_t)b * 131072;
    int r0 = blockIdx.x * 64, c0 = blockIdx.y * 64;   // r = j, c = channel
    int tr = threadIdx.x >> 6, tc = threadIdx.x & 63;
    float scale = rs[b * 1024 + r0 + tc];             // per output column j=r0+tc
    for (int i = 0; i < 16; ++i) {
        int rl = i * 4 + tr;
        tile[rl][tc] = b2f(src[base + (size_t)(r0 + rl) * 128 + c0 + tc]);
    }
    __syncthreads();
    for (int i = 0; i < 16; ++i) {
        int cl = i * 4 + tr;
        dst[base + (size_t)(c0 + cl) * 1024 + r0 + tc] = f2b(tile[tc][cl] * scale);
    }
}

// ---------------------------------------------------------------------------
// QKV conv GEMM with fused 2x2 maxpool for K/V.
// Block: M=192 (4 waves x 48 o), N=128 p (= one h-row pair). K=256.
// q (o<32) -> qf [32][4096] natural; k -> kf [32][1024] pooled; v -> vf [128][1024].
// ---------------------------------------------------------------------------
__global__ __launch_bounds__(256) void qkv_pool(const unsigned short* __restrict__ wqkv,
                                                const float* __restrict__ bias,
                                                const unsigned short* __restrict__ xbt,
                                                unsigned short* __restrict__ qf,
                                                unsigned short* __restrict__ kf,
                                                unsigned short* __restrict__ vf) {
    int b = blockIdx.y, r = blockIdx.x;      // r = h-pair index, p0 = 128*r
    int p0 = r * 128;
    int wave = threadIdx.x >> 6, lane = threadIdx.x & 63;
    int m = lane & 15, quad = lane >> 4;
    const unsigned short* xb = xbt + (size_t)b * 4096 * 256;

    f4v acc[3][8] = {};
    for (int ks = 0; ks < 8; ++ks) {
        int k0 = ks * 32 + quad * 8;
        s8v afr[3];
        for (int mt = 0; mt < 3; ++mt)
            afr[mt] = *(const s8v*)(wqkv + (wave * 48 + mt * 16 + m) * 256 + k0);
        for (int nt = 0; nt < 8; ++nt) {
            s8v bfr = *(const s8v*)(xb + (size_t)(p0 + nt * 16 + m) * 256 + k0);
            for (int mt = 0; mt < 3; ++mt)
                acc[mt][nt] = MFMA16(afr[mt], bfr, acc[mt][nt]);
        }
    }
    for (int mt = 0; mt < 3; ++mt) {
        int obase = wave * 48 + mt * 16;     // 16-aligned: tile entirely q, k, or v
        if (obase < 32) {
            for (int reg = 0; reg < 4; ++reg) {
                int o = obase + quad * 4 + reg;
                float bi = bias[o];
                for (int nt = 0; nt < 8; ++nt)
                    qf[(size_t)b * 131072 + (size_t)o * 4096 + p0 + nt * 16 + m] =
                        f2b(acc[mt][nt][reg] + bi);
            }
        } else {
            for (int reg = 0; reg < 4; ++reg) {
                int o = obase + quad * 4 + reg;
                float bi = bias[o];
                for (int nt = 0; nt < 4; ++nt) {
                    float vv = fmaxf(acc[mt][nt][reg], acc[mt][nt + 4][reg]); // h, h+1
                    float ov = __shfl_xor(vv, 1);                             // w pair
                    if ((m & 1) == 0) {
                        float res = fmaxf(vv, ov) + bi;
                        int w2 = nt * 8 + (m >> 1);
                        int sp = r * 32 + w2;
                        if (o < 64) kf[(size_t)b * 32768 + (size_t)(o - 32) * 1024 + sp] = f2b(res);
                        else        vf[(size_t)b * 131072 + (size_t)(o - 64) * 1024 + sp] = f2b(res);
                    }
                }
            }
        }
    }
}

// ---------------------------------------------------------------------------
// Column softmax stats (base-2 domain): m'_j = max_l S'[l,j],
// rs_j = 1/sum_l 2^(S'-m'_j).  Block = (16 j, batch), grid (64,16).
// ---------------------------------------------------------------------------
__global__ __launch_bounds__(256) void col_stats(const unsigned short* __restrict__ qf,
                                                 const unsigned short* __restrict__ kf,
                                                 float* __restrict__ mg, float* __restrict__ rs) {
    __shared__ float red[4][16], mfin[16];
    int b = blockIdx.y, j0 = blockIdx.x * 16;
    int wave = threadIdx.x >> 6, lane = threadIdx.x & 63;
    int m = lane & 15, quad = lane >> 4;
    const unsigned short* qb = qf + (size_t)b * 131072;
    f4v zero = {0.f, 0.f, 0.f, 0.f};

    s8v kfr = *(const s8v*)(kf + (size_t)b * 32768 + (size_t)(j0 + m) * 32 + quad * 8);

    // phase 1: column max (lane's 4 acc values live in column j0+m)
    float mx = -3e38f;
    for (int it = wave; it < 256; it += 4) {
        s8v afr = *(const s8v*)(qb + (size_t)(it * 16 + m) * 32 + quad * 8);
        f4v s = MFMA16(afr, kfr, zero);
        mx = fmaxf(mx, fmaxf(fmaxf(s[0], s[1]), fmaxf(s[2], s[3])));
    }
    mx = fmaxf(mx, __shfl_xor(mx, 16));
    mx = fmaxf(mx, __shfl_xor(mx, 32));
    if (lane < 16) red[wave][m] = mx;
    __syncthreads();
    if (threadIdx.x < 16) {
        float M = fmaxf(fmaxf(red[0][threadIdx.x], red[1][threadIdx.x]),
                        fmaxf(red[2][threadIdx.x], red[3][threadIdx.x]));
        mg[b * 1024 + j0 + threadIdx.x] = M;
        mfin[threadIdx.x] = M;
    }
    __syncthreads();
    float mj = mfin[m];

    // phase 2: sum of 2^(S'-m')
    float sm = 0.f;
    for (int it = wave; it < 256; it += 4) {
        s8v afr = *(const s8v*)(qb + (size_t)(it * 16 + m) * 32 + quad * 8);
        f4v s = MFMA16(afr, kfr, zero);
        sm += (exp2f(s[0] - mj) + exp2f(s[1] - mj)) +
              (exp2f(s[2] - mj) + exp2f(s[3] - mj));
    }
    sm += __shfl_xor(sm, 16);
    sm += __shfl_xor(sm, 32);
    __syncthreads();
    if (lane < 16) red[wave][m] = sm;
    __syncthreads();
    if (threadIdx.x < 16) {
        float S = (red[0][threadIdx.x] + red[1][threadIdx.x]) +
                  (red[2][threadIdx.x] + red[3][threadIdx.x]);
        rs[b * 1024 + j0 + threadIdx.x] = 1.0f / S;
    }
}

// ---------------------------------------------------------------------------
// Fused attention, transposed-S version.
// Block = 64 l x 128 c, 4 waves (wave strip = 16 l), grid (64, 16) = 1024 blocks.
// St = MFMA(A=K, B=Q) -> lane holds 4 consecutive j for fixed l -> packed b64
// LDS write into PT[l][j] (A-operand layout). PV reads pa as b128. V-fragments
// prefetched ahead of MFMA use. No __syncthreads (PT rows wave-private).
// ---------------------------------------------------------------------------
__global__ __launch_bounds__(256, 4) void attn_fused(const unsigned short* __restrict__ qf,
                                                     const unsigned short* __restrict__ kf,
                                                     const unsigned short* __restrict__ vs,
                                                     const float* __restrict__ mg,
                                                     unsigned short* __restrict__ fa) {
    __shared__ unsigned short PT[64][136];   // 17.4 KB; 272 B rows (b64/b128 aligned)
    int b = blockIdx.y, l0 = blockIdx.x * 64;
    int wave = threadIdx.x >> 6, lane = threadIdx.x & 63;
    int m = lane & 15, quad = lane >> 4;
    const unsigned short* qb = qf + (size_t)b * 131072;
    const unsigned short* kb = kf + (size_t)b * 32768;
    const unsigned short* vb = vs + (size_t)b * 131072;
    const float* mb = mg + b * 1024;
    int ls = wave * 16;                      // wave-private PT rows [ls, ls+16)

    s8v qa = *(const s8v*)(qb + (size_t)(l0 + ls + m) * 32 + quad * 8);
    f4v acc[8] = {};
    f4v zero = {0.f, 0.f, 0.f, 0.f};
    s8v vcur[8];

    for (int jc = 0; jc < 8; ++jc) {
        int j0 = jc * 128;
        // prefetch V ks=0 slice; latency hidden by the S phase below
        for (int ct = 0; ct < 8; ++ct)
            vcur[ct] = *(const s8v*)(vb + (size_t)(ct * 16 + m) * 1024 + j0 + quad * 8);
        // S phase: St[j][l], P = 2^(S'-m'), pack 4 bf16 -> one b64 LDS write
        for (int jt = 0; jt < 8; ++jt) {
            s8v kfr = *(const s8v*)(kb + (size_t)(j0 + jt * 16 + m) * 32 + quad * 8);
            f4v st = MFMA16(kfr, qa, zero);      // row=j local (quad*4+reg), col=l (m)
            float4 mjv = *(const float4*)(mb + j0 + jt * 16 + quad * 4);
            unsigned int u0 = ((unsigned)f2b(exp2f(st[1] - mjv.y)) << 16) |
                              (unsigned)f2b(exp2f(st[0] - mjv.x));
            unsigned int u1 = ((unsigned)f2b(exp2f(st[3] - mjv.w)) << 16) |
                              (unsigned)f2b(exp2f(st[2] - mjv.z));
            uint2 uu; uu.x = u0; uu.y = u1;
            *(uint2*)(&PT[ls + m][jt * 16 + quad * 4]) = uu;
        }
        __threadfence_block();   // order LDS writes before reads (wave-private rows)
        for (int ks = 0; ks < 4; ++ks) {
            s8v pa = *(const s8v*)(&PT[ls + m][ks * 32 + quad * 8]);
            for (int ct = 0; ct < 8; ++ct)
                acc[ct] = MFMA16(pa, vcur[ct], acc[ct]);
            // reload vcur for next slice after MFMA issue (overlaps execution)
            if (ks < 3) {
                int jn = j0 + (ks + 1) * 32;
                for (int ct = 0; ct < 8; ++ct)
                    vcur[ct] = *(const s8v*)(vb + (size_t)(ct * 16 + m) * 1024 + jn + quad * 8);
            }
        }
        __threadfence_block();   // reads done before next chunk's writes (WAR)
    }
    for (int ct = 0; ct < 8; ++ct)
        for (int reg = 0; reg < 4; ++reg) {
            int l = l0 + ls + quad * 4 + reg;
            fa[(size_t)b * 524288 + (size_t)l * 128 + ct * 16 + m] = f2b(acc[ct][reg]);
        }
}

// ---------------------------------------------------------------------------
// Final conv + residual: out[o,p] = gamma*(sum_cc W2[o,cc]*Mview[cc,p] + b2[o]) + x.
// ---------------------------------------------------------------------------
__global__ __launch_bounds__(256) void final_gemm(const unsigned short* __restrict__ w2b,
                                                  const float* __restrict__ v2b,
                                                  const float* __restrict__ gamma,
                                                  const unsigned short* __restrict__ ga,
                                                  const float* __restrict__ x,
                                                  float* __restrict__ out) {
    int b = blockIdx.y, p0 = blockIdx.x * 64;
    int wave = threadIdx.x >> 6, lane = threadIdx.x & 63;
    int m = lane & 15, quad = lane >> 4;
    const unsigned short* gb = ga + (size_t)b * 524288;

    f4v acc[4][4] = {};
    for (int ks = 0; ks < 4; ++ks) {
        int k0 = ks * 32 + quad * 8;
        s8v afr[4], bfr[4];
        for (int mt = 0; mt < 4; ++mt)
            afr[mt] = *(const s8v*)(w2b + (wave * 64 + mt * 16 + m) * 128 + k0);
        for (int nt = 0; nt < 4; ++nt)
            bfr[nt] = *(const s8v*)(gb + (size_t)(p0 + nt * 16 + m) * 128 + k0);
        for (int mt = 0; mt < 4; ++mt)
            for (int nt = 0; nt < 4; ++nt)
                acc[mt][nt] = MFMA16(afr[mt], bfr[nt], acc[mt][nt]);
    }
    float g = gamma[0];
    for (int mt = 0; mt < 4; ++mt) {
        for (int reg = 0; reg < 4; ++reg) {
            int o = wave * 64 + mt * 16 + quad * 4 + reg;
            float bi = v2b[o];
            for (int nt = 0; nt < 4; ++nt) {
                int p = p0 + nt * 16 + m;
                size_t xi = (size_t)b * 1048576 + (size_t)o * 4096 + p;
                out[xi] = g * (acc[mt][nt][reg] + bi) + x[xi];
            }
        }
    }
}

// ---------------------------------------------------------------------------
extern "C" void kernel_launch(void* const* d_in, const int* in_sizes, int n_in,
                              void* d_out, int out_size, void* d_ws, size_t ws_size,
                              hipStream_t stream) {
    const float* x    = (const float*)d_in[0];
    const float* qw   = (const float*)d_in[1];
    const float* qb   = (const float*)d_in[2];
    const float* kw   = (const float*)d_in[3];
    const float* kb   = (const float*)d_in[4];
    const float* vw   = (const float*)d_in[5];
    const float* vb   = (const float*)d_in[6];
    const float* v2w  = (const float*)d_in[7];
    const float* v2b  = (const float*)d_in[8];
    const float* gamma = (const float*)d_in[9];
    float* out = (float*)d_out;

    char* ws = (char*)d_ws;
    size_t off = 0;
    auto alloc = [&](size_t bytes) { size_t o = off; off = (off + bytes + 255) & ~(size_t)255; return o; };
    unsigned short* wqkv = (unsigned short*)(ws + alloc(192 * 256 * 2));
    unsigned short* w2b  = (unsigned short*)(ws + alloc(256 * 128 * 2));
    float*          bias = (float*)(ws + alloc(192 * 4));
    float*          mgp  = (float*)(ws + alloc((size_t)16 * 1024 * 4));
    float*          rs   = (float*)(ws + alloc((size_t)16 * 1024 * 4));
    unsigned short* qf   = (unsigned short*)(ws + alloc((size_t)16 * 131072 * 2));       // 4 MB
    unsigned short* kf   = (unsigned short*)(ws + alloc((size_t)16 * 32768 * 2));        // 1 MB
    unsigned short* vf   = (unsigned short*)(ws + alloc((size_t)16 * 131072 * 2));       // 4 MB
    unsigned short* vt   = (unsigned short*)(ws + alloc((size_t)16 * 131072 * 2));       // 4 MB
    unsigned short* fa   = (unsigned short*)(ws + alloc((size_t)16 * 524288 * 2));       // 16 MB
    char*           big  = ws + alloc((size_t)16 * 4096 * 256 * 2);                      // 32 MB shared
    unsigned short* xbt  = (unsigned short*)big;                    // dead after qkv_pool
    unsigned short* ga   = (unsigned short*)big;                    // written after
    (void)ws_size; (void)in_sizes; (void)n_in; (void)out_size;

    prep_weights<<<321, 256, 0, stream>>>(qw, qb, kw, kb, vw, vb, v2w, wqkv, bias, w2b);
    // x [256][4096] fp32 -> xbt [4096][256] bf16, per batch
    transpose_to_bf16<float><<<dim3(4, 64, 16), 256, 0, stream>>>(x, xbt, 256, 4096);
    qkv_pool<<<dim3(32, 16), 256, 0, stream>>>(wqkv, bias, xbt, qf, kf, vf);
    col_stats<<<dim3(64, 16), 256, 0, stream>>>(qf, kf, mgp, rs);
    // V raw view [1024][128] -> vt [128][1024], fused *rs[j]
    transpose_scale_v<<<dim3(16, 2, 16), 256, 0, stream>>>(vf, rs, vt);
    attn_fused<<<dim3(64, 16), 256, 0, stream>>>(qf, kf, vt, mgp, fa);
    // applied raw view [128][4096] -> ga [4096][128]
    transpose_to_bf16<unsigned short><<<dim3(2, 64, 16), 256, 0, stream>>>(fa, ga, 128, 4096);
    final_gemm<<<dim3(64, 16), 256, 0, stream>>>(w2b, v2b, gamma, ga, x, out);
}

// Round 5
// 315.049 us; speedup vs baseline: 1.2721x; 1.2721x over previous
//
#include <hip/hip_runtime.h>
#include <hip/hip_bf16.h>

// Problem constants: B=16, C=256, H=W=64, LOC=4096, DOWN=1024, C8=32, C2=128.

typedef short s8v __attribute__((ext_vector_type(8)));   // 8 x bf16 bits (4 VGPRs)
typedef float f4v __attribute__((ext_vector_type(4)));   // 4 x fp32 acc

#define MFMA16(a, b, c) __builtin_amdgcn_mfma_f32_16x16x32_bf16((a), (b), (c), 0, 0, 0)
#define LOG2E 1.4426950408889634f

__device__ __forceinline__ unsigned short f2b(float f) {
    __hip_bfloat16 h = __float2bfloat16(f);
    return *reinterpret_cast<unsigned short*>(&h);
}
__device__ __forceinline__ float b2f(unsigned short u) {
    union { unsigned int i; float f; } v; v.i = ((unsigned int)u) << 16; return v.f;
}
__device__ __forceinline__ void async_lds16(const void* g, void* l) {
    __builtin_amdgcn_global_load_lds(
        (const __attribute__((address_space(1))) void*)g,
        (__attribute__((address_space(3))) void*)l, 16, 0, 0);
}

// ---------------------------------------------------------------------------
// Weight prep: concat q/k/v weights -> bf16 [192][256], bias fp32 [192],
// val2_w -> bf16 [256][128]. K rows/bias pre-scaled by log2(e) -> exp2 softmax.
// ---------------------------------------------------------------------------
__global__ void prep_weights(const float* __restrict__ qw, const float* __restrict__ qb,
                             const float* __restrict__ kw, const float* __restrict__ kb,
                             const float* __restrict__ vw, const float* __restrict__ vb,
                             const float* __restrict__ v2w,
                             unsigned short* __restrict__ wqkv, float* __restrict__ bias,
                             unsigned short* __restrict__ w2b) {
    int i = blockIdx.x * 256 + threadIdx.x;
    if (i < 49152) {                       // 192*256
        int r = i >> 8, c = i & 255; float v;
        if (r < 32)       v = qw[r * 256 + c];
        else if (r < 64)  v = kw[(r - 32) * 256 + c] * LOG2E;
        else              v = vw[(r - 64) * 256 + c];
        wqkv[i] = f2b(v);
    } else if (i < 49152 + 32768) {        // 256*128
        int k = i - 49152; w2b[k] = f2b(v2w[k]);
    } else if (i < 49152 + 32768 + 192) {
        int r = i - 49152 - 32768;
        bias[r] = (r < 32) ? qb[r] : (r < 64 ? kb[r - 32] * LOG2E : vb[r - 64]);
    }
}

// ---------------------------------------------------------------------------
// Generic batched transpose: src [R][C] (row-major, per batch) -> dst [C][R] bf16.
// ---------------------------------------------------------------------------
template <typename T>
__global__ __launch_bounds__(256) void transpose_to_bf16(const T* __restrict__ src,
                                                         unsigned short* __restrict__ dst,
                                                         int R, int C) {
    __shared__ float tile[64][65];
    int b = blockIdx.z;
    size_t base = (size_t)b * R * C;
    int r0 = blockIdx.x * 64, c0 = blockIdx.y * 64;
    int tr = threadIdx.x >> 6, tc = threadIdx.x & 63;
    for (int i = 0; i < 16; ++i) {
        int rl = i * 4 + tr;
        T v = src[base + (size_t)(r0 + rl) * C + c0 + tc];
        float f;
        if constexpr (sizeof(T) == 2) f = b2f((unsigned short)v); else f = (float)v;
        tile[rl][tc] = f;
    }
    __syncthreads();
    for (int i = 0; i < 16; ++i) {
        int cl = i * 4 + tr;
        dst[base + (size_t)(c0 + cl) * R + r0 + tc] = f2b(tile[tc][cl]);
    }
}

// ---------------------------------------------------------------------------
// V transpose + column scale + XOR-swizzled store for LDS staging.
// vf raw-view [1024 j][128 c]; output (per batch, per jc-chunk of 128 j):
//   vt_sw[jc][c][g ^ (c&7)][e] = vf[j][c] * rs[j],  j = jc*128 + g*8 + e.
// ---------------------------------------------------------------------------
__global__ __launch_bounds__(256) void transpose_scale_v(const unsigned short* __restrict__ src,
                                                         const float* __restrict__ rs,
                                                         unsigned short* __restrict__ dst) {
    __shared__ float tile[64][65];
    int b = blockIdx.z;
    size_t base = (size_t)b * 131072;
    int r0 = blockIdx.x * 64, c0 = blockIdx.y * 64;   // r = j, c = channel
    int tr = threadIdx.x >> 6, tc = threadIdx.x & 63;
    float scale = rs[b * 1024 + r0 + tc];             // for output column j=r0+tc
    for (int i = 0; i < 16; ++i) {
        int rl = i * 4 + tr;
        tile[rl][tc] = b2f(src[base + (size_t)(r0 + rl) * 128 + c0 + tc]);
    }
    __syncthreads();
    for (int i = 0; i < 16; ++i) {
        int cl = i * 4 + tr;
        int c = c0 + cl;
        int j = r0 + tc;
        int jc = j >> 7, jl = j & 127, g = jl >> 3, e = jl & 7;
        dst[base + jc * 16384 + c * 128 + ((g ^ (c & 7)) << 3) + e] =
            f2b(tile[tc][cl] * scale);
    }
}

// ---------------------------------------------------------------------------
// QKV conv GEMM with fused 2x2 maxpool for K/V.
// ---------------------------------------------------------------------------
__global__ __launch_bounds__(256) void qkv_pool(const unsigned short* __restrict__ wqkv,
                                                const float* __restrict__ bias,
                                                const unsigned short* __restrict__ xbt,
                                                unsigned short* __restrict__ qf,
                                                unsigned short* __restrict__ kf,
                                                unsigned short* __restrict__ vf) {
    int b = blockIdx.y, r = blockIdx.x;      // r = h-pair index, p0 = 128*r
    int p0 = r * 128;
    int wave = threadIdx.x >> 6, lane = threadIdx.x & 63;
    int m = lane & 15, quad = lane >> 4;
    const unsigned short* xb = xbt + (size_t)b * 4096 * 256;

    f4v acc[3][8] = {};
    for (int ks = 0; ks < 8; ++ks) {
        int k0 = ks * 32 + quad * 8;
        s8v afr[3];
        for (int mt = 0; mt < 3; ++mt)
            afr[mt] = *(const s8v*)(wqkv + (wave * 48 + mt * 16 + m) * 256 + k0);
        for (int nt = 0; nt < 8; ++nt) {
            s8v bfr = *(const s8v*)(xb + (size_t)(p0 + nt * 16 + m) * 256 + k0);
            for (int mt = 0; mt < 3; ++mt)
                acc[mt][nt] = MFMA16(afr[mt], bfr, acc[mt][nt]);
        }
    }
    for (int mt = 0; mt < 3; ++mt) {
        int obase = wave * 48 + mt * 16;     // 16-aligned: tile entirely q, k, or v
        if (obase < 32) {
            for (int reg = 0; reg < 4; ++reg) {
                int o = obase + quad * 4 + reg;
                float bi = bias[o];
                for (int nt = 0; nt < 8; ++nt)
                    qf[(size_t)b * 131072 + (size_t)o * 4096 + p0 + nt * 16 + m] =
                        f2b(acc[mt][nt][reg] + bi);
            }
        } else {
            for (int reg = 0; reg < 4; ++reg) {
                int o = obase + quad * 4 + reg;
                float bi = bias[o];
                for (int nt = 0; nt < 4; ++nt) {
                    float vv = fmaxf(acc[mt][nt][reg], acc[mt][nt + 4][reg]); // h, h+1
                    float ov = __shfl_xor(vv, 1);                             // w pair
                    if ((m & 1) == 0) {
                        float res = fmaxf(vv, ov) + bi;
                        int w2 = nt * 8 + (m >> 1);
                        int sp = r * 32 + w2;
                        if (o < 64) kf[(size_t)b * 32768 + (size_t)(o - 32) * 1024 + sp] = f2b(res);
                        else        vf[(size_t)b * 131072 + (size_t)(o - 64) * 1024 + sp] = f2b(res);
                    }
                }
            }
        }
    }
}

// ---------------------------------------------------------------------------
// Column softmax stats (base-2 domain): m'_j = max_l S'[l,j],
// rs_j = 1/sum_l 2^(S'-m'_j). Block = (16 j, batch), grid (64,16).
// ---------------------------------------------------------------------------
__global__ __launch_bounds__(256) void col_stats(const unsigned short* __restrict__ qf,
                                                 const unsigned short* __restrict__ kf,
                                                 float* __restrict__ mg, float* __restrict__ rs) {
    __shared__ float red[4][16], mfin[16];
    int b = blockIdx.y, j0 = blockIdx.x * 16;
    int wave = threadIdx.x >> 6, lane = threadIdx.x & 63;
    int m = lane & 15, quad = lane >> 4;
    const unsigned short* qb = qf + (size_t)b * 131072;
    f4v zero = {0.f, 0.f, 0.f, 0.f};

    s8v kfr = *(const s8v*)(kf + (size_t)b * 32768 + (size_t)(j0 + m) * 32 + quad * 8);

    float mx = -3e38f;
    for (int it = wave; it < 256; it += 4) {
        s8v afr = *(const s8v*)(qb + (size_t)(it * 16 + m) * 32 + quad * 8);
        f4v s = MFMA16(afr, kfr, zero);
        mx = fmaxf(mx, fmaxf(fmaxf(s[0], s[1]), fmaxf(s[2], s[3])));
    }
    mx = fmaxf(mx, __shfl_xor(mx, 16));
    mx = fmaxf(mx, __shfl_xor(mx, 32));
    if (lane < 16) red[wave][m] = mx;
    __syncthreads();
    if (threadIdx.x < 16) {
        float M = fmaxf(fmaxf(red[0][threadIdx.x], red[1][threadIdx.x]),
                        fmaxf(red[2][threadIdx.x], red[3][threadIdx.x]));
        mg[b * 1024 + j0 + threadIdx.x] = M;
        mfin[threadIdx.x] = M;
    }
    __syncthreads();
    float mj = mfin[m];

    float sm = 0.f;
    for (int it = wave; it < 256; it += 4) {
        s8v afr = *(const s8v*)(qb + (size_t)(it * 16 + m) * 32 + quad * 8);
        f4v s = MFMA16(afr, kfr, zero);
        sm += (exp2f(s[0] - mj) + exp2f(s[1] - mj)) +
              (exp2f(s[2] - mj) + exp2f(s[3] - mj));
    }
    sm += __shfl_xor(sm, 16);
    sm += __shfl_xor(sm, 32);
    __syncthreads();
    if (lane < 16) red[wave][m] = sm;
    __syncthreads();
    if (threadIdx.x < 16) {
        float S = (red[0][threadIdx.x] + red[1][threadIdx.x]) +
                  (red[2][threadIdx.x] + red[3][threadIdx.x]);
        rs[b * 1024 + j0 + threadIdx.x] = 1.0f / S;
    }
}

// ---------------------------------------------------------------------------
// Fused attention, V staged in LDS via global_load_lds.
// Block = 128 l x 128 c, 512 threads (8 waves, 16 l each), grid (32,16).
// Per jc (128 j): async-stage V slice (32 KB, swizzled) -> S-phase (K from L2,
// St=MFMA(K,Q), P=2^(S'-m') packed b64 into swizzled PT) -> barrier ->
// PV-phase (pa/vfr ds_read_b128, MFMA) -> barrier (WAR).
// All LDS rows 256 B (aligned); XOR group-swizzle keeps aliasing <= 2-way.
// ---------------------------------------------------------------------------
__global__ __launch_bounds__(512, 4) void attn_fused(const unsigned short* __restrict__ qf,
                                                     const unsigned short* __restrict__ kf,
                                                     const unsigned short* __restrict__ vsw,
                                                     const float* __restrict__ mg,
                                                     unsigned short* __restrict__ fa) {
    __shared__ alignas(16) unsigned short VS[16384];   // 32 KB: [c][g^ (c&7)][e]
    __shared__ alignas(16) unsigned short PT[16384];   // 32 KB: [l][g^ (l&7)][e]
    int b = blockIdx.y, l0 = blockIdx.x * 128;
    int tid = threadIdx.x;
    int wave = tid >> 6, lane = tid & 63;
    int m = lane & 15, quad = lane >> 4;
    int ls = wave * 16;                                // wave's l strip
    const unsigned short* qb = qf + (size_t)b * 131072;
    const unsigned short* kb = kf + (size_t)b * 32768;
    const unsigned short* vb = vsw + (size_t)b * 131072;
    const float* mb = mg + b * 1024;

    s8v qa = *(const s8v*)(qb + (size_t)(l0 + ls + m) * 32 + quad * 8);
    f4v acc[8] = {};
    f4v zero = {0.f, 0.f, 0.f, 0.f};

    for (int jc = 0; jc < 8; ++jc) {
        // --- async stage V slice for this jc: 512 thr x 16 B x 4 rounds ---
        {
            const unsigned short* src = vb + jc * 16384 + tid * 8;
            unsigned short* dstl = VS + tid * 8;
            for (int rnd = 0; rnd < 4; ++rnd)
                async_lds16(src + rnd * 4096, dstl + rnd * 4096);
        }
        // --- S phase (independent of V): P tile into PT ---
        int j0 = jc * 128;
        for (int jt = 0; jt < 8; ++jt) {
            s8v kfr = *(const s8v*)(kb + (size_t)(j0 + jt * 16 + m) * 32 + quad * 8);
            f4v st = MFMA16(kfr, qa, zero);   // St[j=jt*16+quad*4+reg][l=ls+m]
            float4 mjv = *(const float4*)(mb + j0 + jt * 16 + quad * 4);
            unsigned int u0 = ((unsigned)f2b(exp2f(st[1] - mjv.y)) << 16) |
                              (unsigned)f2b(exp2f(st[0] - mjv.x));
            unsigned int u1 = ((unsigned)f2b(exp2f(st[3] - mjv.w)) << 16) |
                              (unsigned)f2b(exp2f(st[2] - mjv.z));
            int l = ls + m;
            int g = jt * 2 + (quad >> 1);               // 8-elem group of j
            int sub = (quad & 1) * 4;                   // b64 = half a group
            uint2 uu; uu.x = u0; uu.y = u1;
            *(uint2*)(&PT[l * 128 + ((g ^ (l & 7)) << 3) + sub]) = uu;
        }
        __syncthreads();   // drains global_load_lds (vmcnt) + LDS writes
        // --- PV phase: all from LDS ---
        for (int ks = 0; ks < 4; ++ks) {
            int l = ls + m;
            int gp = ks * 4 + quad;
            s8v pa = *(const s8v*)(&PT[l * 128 + ((gp ^ (l & 7)) << 3)]);
            for (int ct = 0; ct < 8; ++ct) {
                int c = ct * 16 + m;
                s8v vfr = *(const s8v*)(&VS[c * 128 + ((gp ^ (c & 7)) << 3)]);
                acc[ct] = MFMA16(pa, vfr, acc[ct]);
            }
        }
        __syncthreads();   // WAR: PV reads done before next staging overwrites
    }
    for (int ct = 0; ct < 8; ++ct)
        for (int reg = 0; reg < 4; ++reg) {
            int l = l0 + ls + quad * 4 + reg;
            fa[(size_t)b * 524288 + (size_t)l * 128 + ct * 16 + m] = f2b(acc[ct][reg]);
        }
}

// ---------------------------------------------------------------------------
// Final conv + residual: out[o,p] = gamma*(sum_cc W2[o,cc]*Mview[cc,p] + b2[o]) + x.
// ---------------------------------------------------------------------------
__global__ __launch_bounds__(256) void final_gemm(const unsigned short* __restrict__ w2b,
                                                  const float* __restrict__ v2b,
                                                  const float* __restrict__ gamma,
                                                  const unsigned short* __restrict__ ga,
                                                  const float* __restrict__ x,
                                                  float* __restrict__ out) {
    int b = blockIdx.y, p0 = blockIdx.x * 64;
    int wave = threadIdx.x >> 6, lane = threadIdx.x & 63;
    int m = lane & 15, quad = lane >> 4;
    const unsigned short* gb = ga + (size_t)b * 524288;

    f4v acc[4][4] = {};
    for (int ks = 0; ks < 4; ++ks) {
        int k0 = ks * 32 + quad * 8;
        s8v afr[4], bfr[4];
        for (int mt = 0; mt < 4; ++mt)
            afr[mt] = *(const s8v*)(w2b + (wave * 64 + mt * 16 + m) * 128 + k0);
        for (int nt = 0; nt < 4; ++nt)
            bfr[nt] = *(const s8v*)(gb + (size_t)(p0 + nt * 16 + m) * 128 + k0);
        for (int mt = 0; mt < 4; ++mt)
            for (int nt = 0; nt < 4; ++nt)
                acc[mt][nt] = MFMA16(afr[mt], bfr[nt], acc[mt][nt]);
    }
    float g = gamma[0];
    for (int mt = 0; mt < 4; ++mt) {
        for (int reg = 0; reg < 4; ++reg) {
            int o = wave * 64 + mt * 16 + quad * 4 + reg;
            float bi = v2b[o];
            for (int nt = 0; nt < 4; ++nt) {
                int p = p0 + nt * 16 + m;
                size_t xi = (size_t)b * 1048576 + (size_t)o * 4096 + p;
                out[xi] = g * (acc[mt][nt][reg] + bi) + x[xi];
            }
        }
    }
}

// ---------------------------------------------------------------------------
extern "C" void kernel_launch(void* const* d_in, const int* in_sizes, int n_in,
                              void* d_out, int out_size, void* d_ws, size_t ws_size,
                              hipStream_t stream) {
    const float* x    = (const float*)d_in[0];
    const float* qw   = (const float*)d_in[1];
    const float* qb   = (const float*)d_in[2];
    const float* kw   = (const float*)d_in[3];
    const float* kb   = (const float*)d_in[4];
    const float* vw   = (const float*)d_in[5];
    const float* vb   = (const float*)d_in[6];
    const float* v2w  = (const float*)d_in[7];
    const float* v2b  = (const float*)d_in[8];
    const float* gamma = (const float*)d_in[9];
    float* out = (float*)d_out;

    char* ws = (char*)d_ws;
    size_t off = 0;
    auto alloc = [&](size_t bytes) { size_t o = off; off = (off + bytes + 255) & ~(size_t)255; return o; };
    unsigned short* wqkv = (unsigned short*)(ws + alloc(192 * 256 * 2));
    unsigned short* w2b  = (unsigned short*)(ws + alloc(256 * 128 * 2));
    float*          bias = (float*)(ws + alloc(192 * 4));
    float*          mgp  = (float*)(ws + alloc((size_t)16 * 1024 * 4));
    float*          rs   = (float*)(ws + alloc((size_t)16 * 1024 * 4));
    unsigned short* qf   = (unsigned short*)(ws + alloc((size_t)16 * 131072 * 2));       // 4 MB
    unsigned short* kf   = (unsigned short*)(ws + alloc((size_t)16 * 32768 * 2));        // 1 MB
    unsigned short* vf   = (unsigned short*)(ws + alloc((size_t)16 * 131072 * 2));       // 4 MB
    unsigned short* vt   = (unsigned short*)(ws + alloc((size_t)16 * 131072 * 2));       // 4 MB (swizzled)
    unsigned short* fa   = (unsigned short*)(ws + alloc((size_t)16 * 524288 * 2));       // 16 MB
    char*           big  = ws + alloc((size_t)16 * 4096 * 256 * 2);                      // 32 MB shared
    unsigned short* xbt  = (unsigned short*)big;                    // dead after qkv_pool
    unsigned short* ga   = (unsigned short*)big;                    // written after
    (void)ws_size; (void)in_sizes; (void)n_in; (void)out_size;

    prep_weights<<<321, 256, 0, stream>>>(qw, qb, kw, kb, vw, vb, v2w, wqkv, bias, w2b);
    // x [256][4096] fp32 -> xbt [4096][256] bf16, per batch
    transpose_to_bf16<float><<<dim3(4, 64, 16), 256, 0, stream>>>(x, xbt, 256, 4096);
    qkv_pool<<<dim3(32, 16), 256, 0, stream>>>(wqkv, bias, xbt, qf, kf, vf);
    col_stats<<<dim3(64, 16), 256, 0, stream>>>(qf, kf, mgp, rs);
    // V raw view [1024][128] -> vt swizzled [jc][c][g^(c&7)][e], fused *rs[j]
    transpose_scale_v<<<dim3(16, 2, 16), 256, 0, stream>>>(vf, rs, vt);
    attn_fused<<<dim3(32, 16), 512, 0, stream>>>(qf, kf, vt, mgp, fa);
    // applied raw view [128][4096] -> ga [4096][128]
    transpose_to_bf16<unsigned short><<<dim3(2, 64, 16), 256, 0, stream>>>(fa, ga, 128, 4096);
    final_gemm<<<dim3(64, 16), 256, 0, stream>>>(w2b, v2b, gamma, ga, x, out);
}